// Round 8
// baseline (238.758 us; speedup 1.0000x reference)
//
#include <hip/hip_runtime.h>
#include <hip/hip_bf16.h>

#define LPOS 8192
#define HDIM 128
#define M_TOT 4096          // B*Cin
#define GROW  132           // gp/g row stride (129 used)
#define GELEMS (M_TOT * GROW)        // 540672
#define KSPLIT 32
#define KCHUNK (LPOS / KSPLIT)       // 256 k per block = 4 chunks of 64
#define CUNITS 1024                  // 16-B units per 64-k chunk
#define BUNITS (4 * CUNITS)          // 4096 units = 65536 B LDS

typedef float  f32x4 __attribute__((ext_vector_type(4)));
typedef short  s16x8 __attribute__((ext_vector_type(8)));
typedef unsigned int u32x2 __attribute__((ext_vector_type(2)));
typedef unsigned int u32x4 __attribute__((ext_vector_type(4)));

__device__ __forceinline__ unsigned short bf16_rne(float f) {
    unsigned u = __builtin_bit_cast(unsigned, f);
    u += 0x7fffu + ((u >> 16) & 1u);
    return (unsigned short)(u >> 16);
}

__device__ __forceinline__ s16x8 cvt8(f32x4 a, f32x4 b) {
    s16x8 r;
    r[0] = (short)bf16_rne(a[0]); r[1] = (short)bf16_rne(a[1]);
    r[2] = (short)bf16_rne(a[2]); r[3] = (short)bf16_rne(a[3]);
    r[4] = (short)bf16_rne(b[0]); r[5] = (short)bf16_rne(b[1]);
    r[6] = (short)bf16_rne(b[2]); r[7] = (short)bf16_rne(b[3]);
    return r;
}

__device__ __forceinline__ float sum8(f32x4 a, f32x4 b) {
    return ((a[0] + a[1]) + (a[2] + a[3])) + ((b[0] + b[1]) + (b[2] + b[3]));
}

// ---------------- Kernel 1: SIREN -> h2T -------------------------------------
__global__ __launch_bounds__(256) void k1_siren(
        const float* __restrict__ w1, const float* __restrict__ b1,
        const float* __restrict__ w2, const float* __restrict__ b2,
        unsigned short* __restrict__ h2T) {
    __shared__ float w2sT[HDIM * 129];
    __shared__ __align__(16) float h1s[2][HDIM * 8];
    const int tid = threadIdx.x;
    const int s = tid >> 7;
    const int h = tid & 127;

    for (int idx = tid; idx < HDIM * HDIM; idx += 256)
        w2sT[(idx & 127) * 129 + (idx >> 7)] = w2[idx];

    const int l0 = blockIdx.x * 16 + s * 8;
    const float myw1 = w1[h], myb1 = b1[h];
    #pragma unroll
    for (int ls = 0; ls < 8; ++ls) {
        float rel = -1.0f + (2.0f / 8191.0f) * (float)(l0 + ls);
        h1s[s][h * 8 + ls] = __sinf(30.0f * (rel * myw1 + myb1));
    }
    __syncthreads();

    const float bb = b2[h];
    float acc[8];
    #pragma unroll
    for (int ls = 0; ls < 8; ++ls) acc[ls] = bb;

    for (int j = 0; j < HDIM; ++j) {
        float wv = w2sT[j * 129 + h];
        const f32x4* hp = (const f32x4*)&h1s[s][j * 8];
        f32x4 p0 = hp[0], p1 = hp[1];
        acc[0] += wv * p0[0]; acc[1] += wv * p0[1];
        acc[2] += wv * p0[2]; acc[3] += wv * p0[3];
        acc[4] += wv * p1[0]; acc[5] += wv * p1[1];
        acc[6] += wv * p1[2]; acc[7] += wv * p1[3];
    }

    u32x4 ov;
    #pragma unroll
    for (int q = 0; q < 4; ++q) {
        unsigned lo = bf16_rne(__sinf(30.0f * acc[2 * q]));
        unsigned hi = bf16_rne(__sinf(30.0f * acc[2 * q + 1]));
        ov[q] = lo | (hi << 16);
    }
    const size_t c = (size_t)(l0 >> 6);
    const int k8 = (l0 >> 3) & 7;
    *(u32x4*)(h2T + (c * CUNITS + (size_t)k8 * 128 + h) * 8) = ov;
}

// ---------------- Kernel 2 (templated ablation): partial GEMM ----------------
// MODE bits: 1=LX (x global loads), 2=CV (cvt to bf16), 4=GL (B global_load_lds),
//            8=CP (ds_read B + MFMA + acc stores). FULL = 15.
// Structure = R4's best-known (barrier-free inner loop, 64 KB single-buffer B).
template<int MODE, int REP>
__global__ __launch_bounds__(256, 2) void k2_t(
        const float* __restrict__ x, const unsigned short* __restrict__ h2T,
        unsigned short* __restrict__ gp) {
    constexpr bool LX = (MODE & 1) != 0;
    constexpr bool CV = (MODE & 2) != 0;
    constexpr bool GL = (MODE & 4) != 0;
    constexpr bool CP = (MODE & 8) != 0;

    __shared__ unsigned short lds[BUNITS * 8];     // 65536 B

    const int lane = threadIdx.x & 63;
    const int wv   = threadIdx.x >> 6;
    const int r    = lane & 15;
    const int kg   = lane >> 4;
    const int m0   = blockIdx.x * 128;
    const int y    = blockIdx.y;
    const int kc   = y * KCHUNK;

    const float* xpa = x + (size_t)(m0 + wv * 32 + r) * LPOS + kc + kg * 8;
    const float* xpb = xpa + 16 * LPOS;

    f32x4 xr[2][2][4];
    if constexpr (!LX) {
        #pragma unroll
        for (int a = 0; a < 2; ++a)
            #pragma unroll
            for (int b = 0; b < 2; ++b)
                #pragma unroll
                for (int cq = 0; cq < 4; ++cq) { f32x4 z = {0.f,0.f,0.f,0.f}; xr[a][b][cq] = z; }
    }

#define LOADX(SL, IT) do { \
        xr[SL][0][0] = *(const f32x4*)(xpa + (IT) * 64);      \
        xr[SL][0][1] = *(const f32x4*)(xpa + (IT) * 64 + 4);  \
        xr[SL][0][2] = *(const f32x4*)(xpa + (IT) * 64 + 32); \
        xr[SL][0][3] = *(const f32x4*)(xpa + (IT) * 64 + 36); \
        xr[SL][1][0] = *(const f32x4*)(xpb + (IT) * 64);      \
        xr[SL][1][1] = *(const f32x4*)(xpb + (IT) * 64 + 4);  \
        xr[SL][1][2] = *(const f32x4*)(xpb + (IT) * 64 + 32); \
        xr[SL][1][3] = *(const f32x4*)(xpb + (IT) * 64 + 36); \
    } while (0)

    f32x4 acc[2][8];
    #pragma unroll
    for (int s = 0; s < 2; ++s)
        #pragma unroll
        for (int t = 0; t < 8; ++t) { f32x4 z = {0.f,0.f,0.f,0.f}; acc[s][t] = z; }
    float sacc0 = 0.f, sacc1 = 0.f;
    const s16x8 zer = {0,0,0,0,0,0,0,0};

    for (int rep = 0; rep < REP; ++rep) {
        if constexpr (GL) {
            const unsigned short* src = h2T + (size_t)y * (BUNITS * 8);
            #pragma unroll
            for (int j = 0; j < 16; ++j) {
                const int U = j * 256 + threadIdx.x;
                __builtin_amdgcn_global_load_lds(
                    (const unsigned int*)(src + (size_t)U * 8),
                    (unsigned int*)&lds[U * 8], 16, 0, 0);
            }
        }
        if constexpr (LX) { LOADX(0, 0); LOADX(1, 1); }
        __syncthreads();

        #pragma unroll
        for (int it = 0; it < 4; ++it) {
            const int sl = it & 1;
            s16x8 a0lo = zer, a0hi = zer, a1lo = zer, a1hi = zer;
            if constexpr (CV) {
                a0lo = cvt8(xr[sl][0][0], xr[sl][0][1]);
                a0hi = cvt8(xr[sl][0][2], xr[sl][0][3]);
                a1lo = cvt8(xr[sl][1][0], xr[sl][1][1]);
                a1hi = cvt8(xr[sl][1][2], xr[sl][1][3]);
            }
            if constexpr (LX) {
                sacc0 += sum8(xr[sl][0][0], xr[sl][0][1]) + sum8(xr[sl][0][2], xr[sl][0][3]);
                sacc1 += sum8(xr[sl][1][0], xr[sl][1][1]) + sum8(xr[sl][1][2], xr[sl][1][3]);
            }
            if constexpr (LX) { if (it + 2 < 4) LOADX(sl, it + 2); }

            if constexpr (CP) {
                #pragma unroll
                for (int t = 0; t < 8; ++t) {
                    s16x8 blo = *(const s16x8*)&lds[((size_t)it * CUNITS + kg * 128 + t * 16 + r) * 8];
                    s16x8 bhi = *(const s16x8*)&lds[((size_t)it * CUNITS + (kg + 4) * 128 + t * 16 + r) * 8];
                    acc[0][t] = __builtin_amdgcn_mfma_f32_16x16x32_bf16(a0lo, blo, acc[0][t], 0, 0, 0);
                    acc[0][t] = __builtin_amdgcn_mfma_f32_16x16x32_bf16(a0hi, bhi, acc[0][t], 0, 0, 0);
                    acc[1][t] = __builtin_amdgcn_mfma_f32_16x16x32_bf16(a1lo, blo, acc[1][t], 0, 0, 0);
                    acc[1][t] = __builtin_amdgcn_mfma_f32_16x16x32_bf16(a1hi, bhi, acc[1][t], 0, 0, 0);
                }
            }
        }
        __syncthreads();   // protect lds before next rep restages
    }
#undef LOADX

    // keep LDS allocated in load-only variant (occupancy parity across variants)
    if constexpr (!GL && !CP) {
        if (__builtin_bit_cast(unsigned, sacc0) == 0xDEADBEEFu) lds[0] = 1;
    }

    unsigned short* gpy = gp + (size_t)y * GELEMS;
    if constexpr (CP) {
        #pragma unroll
        for (int s = 0; s < 2; ++s) {
            #pragma unroll
            for (int t = 0; t < 8; ++t) {
                const int col = t * 16 + r;
                #pragma unroll
                for (int q = 0; q < 4; ++q) {
                    const int row = m0 + wv * 32 + s * 16 + kg * 4 + q;
                    gpy[(size_t)row * GROW + col] = bf16_rne(acc[s][t][q]);
                }
            }
        }
    }
    // col 128 row-sums (always stored: keeps LX loads live in all variants)
    sacc0 += __shfl_xor(sacc0, 16); sacc0 += __shfl_xor(sacc0, 32);
    sacc1 += __shfl_xor(sacc1, 16); sacc1 += __shfl_xor(sacc1, 32);
    if (kg == 0) {
        gpy[(size_t)(m0 + wv * 32 + r) * GROW + 128]      = bf16_rne(sacc0);
        gpy[(size_t)(m0 + wv * 32 + 16 + r) * GROW + 128] = bf16_rne(sacc1);
    }
}

// ---------------- reduce: g[f] = sum_y gp[y][f]  (bf16 -> f32) ---------------
__global__ __launch_bounds__(256) void reduce_g(
        const unsigned short* __restrict__ gp, float* __restrict__ g) {
    const int t = blockIdx.x * 256 + threadIdx.x;
    const unsigned int* p = (const unsigned int*)gp;
    float s0 = 0.f, s1 = 0.f, s2 = 0.f, s3 = 0.f;
    #pragma unroll 8
    for (int y = 0; y < KSPLIT; ++y) {
        u32x2 v = *(const u32x2*)(p + (size_t)y * (GELEMS / 2) + (size_t)t * 2);
        s0 += __builtin_bit_cast(float, v[0] << 16);
        s1 += __builtin_bit_cast(float, v[0] & 0xffff0000u);
        s2 += __builtin_bit_cast(float, v[1] << 16);
        s3 += __builtin_bit_cast(float, v[1] & 0xffff0000u);
    }
    f32x4 o = {s0, s1, s2, s3};
    *(f32x4*)(g + (size_t)t * 4) = o;
}

// ---------------- Kernel 3: out[b,o] = sum_{i,h} g[b,i,h]*w3e[o*64+i,h] ------
__global__ __launch_bounds__(256) void k3_contract(
        const float* __restrict__ g, const float* __restrict__ w3,
        const float* __restrict__ b3, const float* __restrict__ bias,
        float* __restrict__ out) {
    const int b = blockIdx.x >> 6;
    const int o = blockIdx.x & 63;
    const int t = threadIdx.x;
    const int i = t >> 2;
    const int q = t & 3;
    __shared__ float red[64];

    const float* gi = g + (size_t)(b * 64 + i) * GROW + q * 32;
    const float* wi = w3 + (size_t)(o * 64 + i) * HDIM + q * 32;
    float acc = 0.f;
    #pragma unroll
    for (int j = 0; j < 8; ++j) {
        f32x4 gv = *(const f32x4*)(gi + j * 4);
        f32x4 wv = *(const f32x4*)(wi + j * 4);
        acc += gv[0] * wv[0] + gv[1] * wv[1] + gv[2] * wv[2] + gv[3] * wv[3];
    }
    if (q == 0) acc += g[(size_t)(b * 64 + i) * GROW + 128] * b3[o * 64 + i];
    acc += __shfl_xor(acc, 1);
    acc += __shfl_xor(acc, 2);
    if (q == 0) red[i] = acc;
    __syncthreads();
    if (t < 64) {
        float v = red[t];
        v += __shfl_xor(v, 1);  v += __shfl_xor(v, 2);  v += __shfl_xor(v, 4);
        v += __shfl_xor(v, 8);  v += __shfl_xor(v, 16); v += __shfl_xor(v, 32);
        if (t == 0) out[blockIdx.x] = v + bias[o];
    }
}

extern "C" void kernel_launch(void* const* d_in, const int* in_sizes, int n_in,
                              void* d_out, int out_size, void* d_ws, size_t ws_size,
                              hipStream_t stream) {
    (void)in_sizes; (void)n_in; (void)out_size; (void)ws_size;
    const float* x    = (const float*)d_in[0];
    const float* w1   = (const float*)d_in[1];
    const float* b1   = (const float*)d_in[2];
    const float* w2   = (const float*)d_in[3];
    const float* b2   = (const float*)d_in[4];
    const float* w3   = (const float*)d_in[5];
    const float* b3   = (const float*)d_in[6];
    const float* bias = (const float*)d_in[7];
    float* out = (float*)d_out;

    char* ws = (char*)d_ws;
    unsigned short* h2T = (unsigned short*)ws;                 // 2.10 MB
    const size_t H2T_BYTES = (size_t)(LPOS / 64) * CUNITS * 16;
    const size_t GP_BYTES  = (size_t)KSPLIT * GELEMS * 2;      // 34.6 MB
    unsigned short* gp      = (unsigned short*)(ws + H2T_BYTES);
    float*          g       = (float*)(ws + H2T_BYTES + GP_BYTES);
    const size_t G_BYTES    = (size_t)GELEMS * 4;              // 2.16 MB
    unsigned short* gp_ldx  = (unsigned short*)(ws + H2T_BYTES + GP_BYTES + G_BYTES);
    unsigned short* gp_mem  = (unsigned short*)(ws + H2T_BYTES + 2 * GP_BYTES + G_BYTES);
    unsigned short* gp_comp = (unsigned short*)(ws + H2T_BYTES + 3 * GP_BYTES + G_BYTES);

    // real pipeline first (unperturbed by ablation variants)
    k1_siren<<<LPOS / 16, 256, 0, stream>>>(w1, b1, w2, b2, h2T);
    k2_t<15, 1><<<dim3(M_TOT / 128, KSPLIT), 256, 0, stream>>>(x, h2T, gp);   // FULL
    reduce_g<<<GELEMS / 4 / 256, 256, 0, stream>>>(gp, g);
    k3_contract<<<64 * 64, 256, 0, stream>>>(g, w3, b3, bias, out);

    // ablation probes (write only their own scratch strips)
    k2_t<1, 4><<<dim3(M_TOT / 128, KSPLIT), 256, 0, stream>>>(x, h2T, gp_ldx);   // LX only, x4
    k2_t<5, 2><<<dim3(M_TOT / 128, KSPLIT), 256, 0, stream>>>(x, h2T, gp_mem);   // LX+GL,  x2
    k2_t<12, 4><<<dim3(M_TOT / 128, KSPLIT), 256, 0, stream>>>(x, h2T, gp_comp); // GL+CP,  x4
}

// Round 9
// 70.733 us; speedup vs baseline: 3.3755x; 3.3755x over previous
//
#include <hip/hip_runtime.h>
#include <hip/hip_bf16.h>

#define LPOS 8192
#define HDIM 128
#define M_TOT 4096          // B*Cin
#define GROW  136           // gp row stride (h 0..127, col128 = rowsum, 129..135 pad) — 16B-aligned rows
#define GELEMS (M_TOT * GROW)        // 557056
#define KSPLIT 32
#define KCHUNK (LPOS / KSPLIT)       // 256 k per block = 4 chunks of 64
#define CUNITS 1024                  // 16-B units per 64-k chunk
#define BUNITS (4 * CUNITS)          // 4096 units = 65536 B LDS

typedef float  f32x4 __attribute__((ext_vector_type(4)));
typedef short  s16x8 __attribute__((ext_vector_type(8)));
typedef unsigned int u32x4 __attribute__((ext_vector_type(4)));

__device__ __forceinline__ unsigned short bf16_rne(float f) {
    unsigned u = __builtin_bit_cast(unsigned, f);
    u += 0x7fffu + ((u >> 16) & 1u);
    return (unsigned short)(u >> 16);
}
__device__ __forceinline__ float bf16f(unsigned short v) {
    return __builtin_bit_cast(float, (unsigned)v << 16);
}

__device__ __forceinline__ s16x8 cvt8(f32x4 a, f32x4 b) {
    s16x8 r;
    r[0] = (short)bf16_rne(a[0]); r[1] = (short)bf16_rne(a[1]);
    r[2] = (short)bf16_rne(a[2]); r[3] = (short)bf16_rne(a[3]);
    r[4] = (short)bf16_rne(b[0]); r[5] = (short)bf16_rne(b[1]);
    r[6] = (short)bf16_rne(b[2]); r[7] = (short)bf16_rne(b[3]);
    return r;
}

__device__ __forceinline__ float sum8(f32x4 a, f32x4 b) {
    return ((a[0] + a[1]) + (a[2] + a[3])) + ((b[0] + b[1]) + (b[2] + b[3]));
}

// ---------------- Kernel 1: SIREN -> h2T -------------------------------------
// h2T 16-B units: unit = chunk*1024 + k8*128 + h   (chunk = l/64, k8 = (l/8)%8)
__global__ __launch_bounds__(256) void k1_siren(
        const float* __restrict__ w1, const float* __restrict__ b1,
        const float* __restrict__ w2, const float* __restrict__ b2,
        unsigned short* __restrict__ h2T) {
    __shared__ float w2sT[HDIM * 129];
    __shared__ __align__(16) float h1s[2][HDIM * 8];
    const int tid = threadIdx.x;
    const int s = tid >> 7;
    const int h = tid & 127;

    for (int idx = tid; idx < HDIM * HDIM; idx += 256)
        w2sT[(idx & 127) * 129 + (idx >> 7)] = w2[idx];

    const int l0 = blockIdx.x * 16 + s * 8;
    const float myw1 = w1[h], myb1 = b1[h];
    #pragma unroll
    for (int ls = 0; ls < 8; ++ls) {
        float rel = -1.0f + (2.0f / 8191.0f) * (float)(l0 + ls);
        h1s[s][h * 8 + ls] = __sinf(30.0f * (rel * myw1 + myb1));
    }
    __syncthreads();

    const float bb = b2[h];
    float acc[8];
    #pragma unroll
    for (int ls = 0; ls < 8; ++ls) acc[ls] = bb;

    for (int j = 0; j < HDIM; ++j) {
        float wv = w2sT[j * 129 + h];
        const f32x4* hp = (const f32x4*)&h1s[s][j * 8];
        f32x4 p0 = hp[0], p1 = hp[1];
        acc[0] += wv * p0[0]; acc[1] += wv * p0[1];
        acc[2] += wv * p0[2]; acc[3] += wv * p0[3];
        acc[4] += wv * p1[0]; acc[5] += wv * p1[1];
        acc[6] += wv * p1[2]; acc[7] += wv * p1[3];
    }

    u32x4 ov;
    #pragma unroll
    for (int q = 0; q < 4; ++q) {
        unsigned lo = bf16_rne(__sinf(30.0f * acc[2 * q]));
        unsigned hi = bf16_rne(__sinf(30.0f * acc[2 * q + 1]));
        ov[q] = lo | (hi << 16);
    }
    const size_t c = (size_t)(l0 >> 6);
    const int k8 = (l0 >> 3) & 7;
    *(u32x4*)(h2T + (c * CUNITS + (size_t)k8 * 128 + h) * 8) = ov;
}

// ---------------- Kernel 2: partial GEMM (R5/R8-FULL best-known, unchanged) --
__global__ __launch_bounds__(256, 2) void k2_gemm(
        const float* __restrict__ x, const unsigned short* __restrict__ h2T,
        unsigned short* __restrict__ gp) {
    __shared__ unsigned short lds[BUNITS * 8];     // 65536 B

    const int lane = threadIdx.x & 63;
    const int wv   = threadIdx.x >> 6;
    const int r    = lane & 15;
    const int kg   = lane >> 4;
    const int m0   = blockIdx.x * 128;
    const int y    = blockIdx.y;
    const int kc   = y * KCHUNK;

    const float* xpa = x + (size_t)(m0 + wv * 32 + r) * LPOS + kc + kg * 8;
    const float* xpb = xpa + 16 * LPOS;

    f32x4 xr[2][2][4];

#define LOADX(SL, IT) do { \
        xr[SL][0][0] = *(const f32x4*)(xpa + (IT) * 64);      \
        xr[SL][0][1] = *(const f32x4*)(xpa + (IT) * 64 + 4);  \
        xr[SL][0][2] = *(const f32x4*)(xpa + (IT) * 64 + 32); \
        xr[SL][0][3] = *(const f32x4*)(xpa + (IT) * 64 + 36); \
        xr[SL][1][0] = *(const f32x4*)(xpb + (IT) * 64);      \
        xr[SL][1][1] = *(const f32x4*)(xpb + (IT) * 64 + 4);  \
        xr[SL][1][2] = *(const f32x4*)(xpb + (IT) * 64 + 32); \
        xr[SL][1][3] = *(const f32x4*)(xpb + (IT) * 64 + 36); \
    } while (0)

    // B stage: 64 KB, 16 issues/thread
    {
        const unsigned short* src = h2T + (size_t)y * (BUNITS * 8);
        #pragma unroll
        for (int j = 0; j < 16; ++j) {
            const int U = j * 256 + threadIdx.x;
            __builtin_amdgcn_global_load_lds(
                (const unsigned int*)(src + (size_t)U * 8),
                (unsigned int*)&lds[U * 8], 16, 0, 0);
        }
    }
    LOADX(0, 0); LOADX(1, 1);

    f32x4 acc[2][8];
    #pragma unroll
    for (int s = 0; s < 2; ++s)
        #pragma unroll
        for (int t = 0; t < 8; ++t) { f32x4 z = {0.f,0.f,0.f,0.f}; acc[s][t] = z; }
    float sacc0 = 0.f, sacc1 = 0.f;

    __syncthreads();

    #pragma unroll
    for (int it = 0; it < 4; ++it) {
        const int sl = it & 1;
        s16x8 a0lo = cvt8(xr[sl][0][0], xr[sl][0][1]);
        s16x8 a0hi = cvt8(xr[sl][0][2], xr[sl][0][3]);
        s16x8 a1lo = cvt8(xr[sl][1][0], xr[sl][1][1]);
        s16x8 a1hi = cvt8(xr[sl][1][2], xr[sl][1][3]);
        sacc0 += sum8(xr[sl][0][0], xr[sl][0][1]) + sum8(xr[sl][0][2], xr[sl][0][3]);
        sacc1 += sum8(xr[sl][1][0], xr[sl][1][1]) + sum8(xr[sl][1][2], xr[sl][1][3]);
        if (it + 2 < 4) LOADX(sl, it + 2);

        #pragma unroll
        for (int t = 0; t < 8; ++t) {
            s16x8 blo = *(const s16x8*)&lds[((size_t)it * CUNITS + kg * 128 + t * 16 + r) * 8];
            s16x8 bhi = *(const s16x8*)&lds[((size_t)it * CUNITS + (kg + 4) * 128 + t * 16 + r) * 8];
            acc[0][t] = __builtin_amdgcn_mfma_f32_16x16x32_bf16(a0lo, blo, acc[0][t], 0, 0, 0);
            acc[0][t] = __builtin_amdgcn_mfma_f32_16x16x32_bf16(a0hi, bhi, acc[0][t], 0, 0, 0);
            acc[1][t] = __builtin_amdgcn_mfma_f32_16x16x32_bf16(a1lo, blo, acc[1][t], 0, 0, 0);
            acc[1][t] = __builtin_amdgcn_mfma_f32_16x16x32_bf16(a1hi, bhi, acc[1][t], 0, 0, 0);
        }
    }
#undef LOADX

    unsigned short* gpy = gp + (size_t)y * GELEMS;
    #pragma unroll
    for (int s = 0; s < 2; ++s) {
        #pragma unroll
        for (int t = 0; t < 8; ++t) {
            const int col = t * 16 + r;
            #pragma unroll
            for (int q = 0; q < 4; ++q) {
                const int row = m0 + wv * 32 + s * 16 + kg * 4 + q;
                gpy[(size_t)row * GROW + col] = bf16_rne(acc[s][t][q]);
            }
        }
    }
    sacc0 += __shfl_xor(sacc0, 16); sacc0 += __shfl_xor(sacc0, 32);
    sacc1 += __shfl_xor(sacc1, 16); sacc1 += __shfl_xor(sacc1, 32);
    if (kg == 0) {
        gpy[(size_t)(m0 + wv * 32 + r) * GROW + 128]      = bf16_rne(sacc0);
        gpy[(size_t)(m0 + wv * 32 + 16 + r) * GROW + 128] = bf16_rne(sacc1);
    }
}

// ---------------- Kernel 3: per-i MFMA contraction, reads gp directly --------
// bid = i*4 + yg. out_part[bid][b][o] = sum_{y in yg*8..+8, h<128}
//   gp[y][b*64+i][h] * w3bf[o*64+i][h]  + (sum_y rowsum) * b3[o*64+i]
// A staged per-y (16 KB, XOR-swizzled, dbuf); B built once, frags hoisted.
__global__ __launch_bounds__(256, 3) void k3_mm(
        const unsigned short* __restrict__ gp, const float* __restrict__ w3,
        const float* __restrict__ b3, float* __restrict__ part) {
    __shared__ unsigned short As[2][64 * 128];   // 2 x 16 KB
    __shared__ unsigned short Bs[64 * 128];      // 16 KB
    __shared__ float b3s[64];
    __shared__ float sls[64];

    const int bid = blockIdx.x;
    const int i   = bid >> 2;
    const int y0  = (bid & 3) * 8;
    const int t    = threadIdx.x;
    const int lane = t & 63;
    const int w    = t >> 6;
    const int r    = lane & 15;
    const int kg   = lane >> 4;

    // B-tile: rows o (64) x h (128) bf16, swizzled; from w3 rows o*64+i
    #pragma unroll
    for (int p = 0; p < 4; ++p) {
        const int row  = p * 16 + (t >> 4);
        const int gran = t & 15;
        const float* src = w3 + (size_t)(row * 64 + i) * HDIM + gran * 8;
        f32x4 v0 = *(const f32x4*)src;
        f32x4 v1 = *(const f32x4*)(src + 4);
        *(s16x8*)&Bs[row * 128 + ((gran ^ (row & 7)) * 8)] = cvt8(v0, v1);
    }
    if (t < 64) b3s[t] = b3[t * 64 + i];

    float sreg = 0.f;
    auto stageA = [&](int y, int d) {
        const unsigned short* src = gp + (size_t)y * GELEMS + (size_t)i * GROW;
        #pragma unroll
        for (int p = 0; p < 4; ++p) {
            const int b    = p * 16 + (t >> 4);
            const int gran = t & 15;
            s16x8 v = *(const s16x8*)(src + (size_t)b * (64 * GROW) + gran * 8);
            *(s16x8*)&As[d][b * 128 + ((gran ^ (b & 7)) * 8)] = v;
        }
        if (t < 64) sreg += bf16f(src[(size_t)t * (64 * GROW) + 128]);
    };

    stageA(y0, 0);
    __syncthreads();

    // hoist y-invariant B fragments: wave tile = 16 b x 64 o
    s16x8 bfr[4][4];
    #pragma unroll
    for (int ct = 0; ct < 4; ++ct) {
        const int o = ct * 16 + r;
        #pragma unroll
        for (int ks = 0; ks < 4; ++ks)
            bfr[ct][ks] = *(const s16x8*)&Bs[o * 128 + (((ks * 4 + kg) ^ (o & 7)) * 8)];
    }

    f32x4 acc[4];
    #pragma unroll
    for (int ct = 0; ct < 4; ++ct) { f32x4 z = {0.f,0.f,0.f,0.f}; acc[ct] = z; }

    const int bA = w * 16 + r;
    #pragma unroll
    for (int yy = 0; yy < 8; ++yy) {
        if (yy + 1 < 8) stageA(y0 + yy + 1, (yy + 1) & 1);
        const unsigned short* buf = &As[yy & 1][0];
        s16x8 af[4];
        #pragma unroll
        for (int ks = 0; ks < 4; ++ks)
            af[ks] = *(const s16x8*)&buf[bA * 128 + (((ks * 4 + kg) ^ (bA & 7)) * 8)];
        #pragma unroll
        for (int ct = 0; ct < 4; ++ct)
            #pragma unroll
            for (int ks = 0; ks < 4; ++ks)
                acc[ct] = __builtin_amdgcn_mfma_f32_16x16x32_bf16(af[ks], bfr[ct][ks], acc[ct], 0, 0, 0);
        __syncthreads();
    }

    if (t < 64) sls[t] = sreg;
    __syncthreads();

    float* po = part + (size_t)bid * 4096;
    #pragma unroll
    for (int ct = 0; ct < 4; ++ct) {
        const int o = ct * 16 + r;
        #pragma unroll
        for (int q = 0; q < 4; ++q) {
            const int b = w * 16 + kg * 4 + q;
            po[b * 64 + o] = acc[ct][q] + sls[b] * b3s[o];
        }
    }
}

// ---------------- Kernel 4: out[idx] = bias[idx&63] + sum_p part[p][idx] -----
__global__ __launch_bounds__(256) void k4_final(
        const float* __restrict__ part, const float* __restrict__ bias,
        float* __restrict__ out) {
    const int idx = blockIdx.x * 256 + threadIdx.x;
    float s = bias[idx & 63];
    #pragma unroll 8
    for (int p = 0; p < 256; ++p)
        s += part[(size_t)p * 4096 + idx];
    out[idx] = s;
}

extern "C" void kernel_launch(void* const* d_in, const int* in_sizes, int n_in,
                              void* d_out, int out_size, void* d_ws, size_t ws_size,
                              hipStream_t stream) {
    (void)in_sizes; (void)n_in; (void)out_size; (void)ws_size;
    const float* x    = (const float*)d_in[0];
    const float* w1   = (const float*)d_in[1];
    const float* b1   = (const float*)d_in[2];
    const float* w2   = (const float*)d_in[3];
    const float* b2   = (const float*)d_in[4];
    const float* w3   = (const float*)d_in[5];
    const float* b3   = (const float*)d_in[6];
    const float* bias = (const float*)d_in[7];
    float* out = (float*)d_out;

    char* ws = (char*)d_ws;
    unsigned short* h2T = (unsigned short*)ws;                          // 2.10 MB
    const size_t H2T_BYTES = (size_t)(LPOS / 64) * CUNITS * 16;
    unsigned short* gp = (unsigned short*)(ws + H2T_BYTES);             // 35.7 MB
    const size_t GP_BYTES = (size_t)KSPLIT * GELEMS * 2;
    float* part = (float*)(ws + H2T_BYTES + GP_BYTES);                  // 4 MB

    k1_siren<<<LPOS / 16, 256, 0, stream>>>(w1, b1, w2, b2, h2T);
    k2_gemm<<<dim3(M_TOT / 128, KSPLIT), 256, 0, stream>>>(x, h2T, gp);
    k3_mm<<<256, 256, 0, stream>>>(gp, w3, b3, part);
    k4_final<<<16, 256, 0, stream>>>(part, bias, out);
}